// Round 12
// baseline (264.367 us; speedup 1.0000x reference)
//
#include <hip/hip_runtime.h>

typedef unsigned short u16;
typedef __attribute__((ext_vector_type(8))) short short8;
typedef __attribute__((ext_vector_type(16))) short short16;
typedef __attribute__((ext_vector_type(4))) float float4v;

__device__ __forceinline__ u16 f2bf(float f) {
    unsigned u = __float_as_uint(f);
    u += 0x7FFFu + ((u >> 16) & 1u);   // RNE
    return (u16)(u >> 16);
}
__device__ __forceinline__ float bf2f(u16 u) {
    return __uint_as_float(((unsigned)u) << 16);
}

// ---------------------------------------------------------------------------
// Module .bss intermediates. NOTE: these may ONLY be referenced from device
// code — passing them as kernel args from host passes the host shadow
// address (round 11's GPU fault).
// ---------------------------------------------------------------------------
__device__ float g_maxout[4 * 32 * 4096];   // 2 MB fp32
__device__ float g_q[16384];
__device__ float g_qmean[16384];
__device__ float g_lit[128];
__device__ float g_sigfac[16384];
__device__ __align__(32) u16 g_Kw_bf[65536];          // K_w  bf16
__device__ __align__(32) u16 g_KSAw_bf[16384];        // KSA_w bf16
__device__ __align__(32) u16 g_Kx[4 * 256 * 16384];   // Kx bf16, 33.5 MB
__device__ __align__(32) u16 g_shT[4 * 16384 * 256];  // shallow^T [b][p][c]
__device__ __align__(32) u16 g_dpT[4 * 4096 * 512];   // deep^T    [b][p][c]

// Zero lit + convert both weight matrices to bf16.
__global__ __launch_bounds__(256) void prep_kernel(
    const float* __restrict__ Kw, const float* __restrict__ KSAw)
{
    const int idx = blockIdx.x * 256 + threadIdx.x;
    if (idx < 128) g_lit[idx] = 0.f;
    if (idx < 65536) g_Kw_bf[idx] = f2bf(Kw[idx]);
    if (idx < 16384) g_KSAw_bf[idx] = f2bf(KSAw[idx]);
}

// ---------------------------------------------------------------------------
// Tiled transpose+cvt core: X[b][C][P] fp32 -> XT[b][P][C] bf16, 64x64 tile.
// Destination pointer is a device-side symbol reference (see note above).
// ---------------------------------------------------------------------------
template <int C, int P>
__device__ __forceinline__ void transpose_body(
    const float* __restrict__ X, u16* __restrict__ XT)
{
    __shared__ float tile[64][65];
    const int t = threadIdx.x;
    const int p0 = blockIdx.x << 6;
    const int c0 = blockIdx.y << 6;
    const int b = blockIdx.z;
    const float* Xb = X + (long long)b * C * P;
    u16* Tb = XT + (long long)b * C * P;

    const int pl = t & 63;
    const int cb = (t >> 6) << 4;       // 0,16,32,48
#pragma unroll
    for (int i = 0; i < 16; ++i)
        tile[cb + i][pl] = Xb[(long long)(c0 + cb + i) * P + p0 + pl];
    __syncthreads();

    const int pl2 = t >> 2;             // 0..63
    const int cb2 = (t & 3) << 4;       // 0,16,32,48
    short16 pack;
#pragma unroll
    for (int i = 0; i < 16; ++i)
        pack[i] = (short)f2bf(tile[cb2 + i][pl2]);
    *(short16*)&Tb[(long long)(p0 + pl2) * C + c0 + cb2] = pack;
}

__global__ __launch_bounds__(256) void transpose_sh(const float* __restrict__ X)
{
    transpose_body<256, 16384>(X, g_shT);
}
__global__ __launch_bounds__(256) void transpose_dp(const float* __restrict__ X)
{
    transpose_body<512, 4096>(X, g_dpT);
}

// ---------------------------------------------------------------------------
// Deep conv via MFMA from transposed bf16: b-frag = one 16B load.
// maxout[b][o][p] = sum_c KSA_w[o][c]*deep[b][c][p]+bias. M=32,K=512,N=4096.
// ---------------------------------------------------------------------------
__global__ __launch_bounds__(256) void gemm_deep(const float* __restrict__ Bias)
{
    const int t = threadIdx.x;
    const int wave = t >> 6, lane = t & 63;
    const int quad = lane >> 4, n16 = lane & 15;
    const int b = blockIdx.y;
    const int p = blockIdx.x * 64 + wave * 16 + n16;
    const u16* bt = g_dpT + ((((long long)(b << 12)) + p) << 9);

    float4v acc[2];
#pragma unroll
    for (int i = 0; i < 2; i++) acc[i] = (float4v){0.f, 0.f, 0.f, 0.f};

    for (int kb = 0; kb < 16; kb++) {
        const int kbase = (kb << 5) + (quad << 3);
        const short8 bfrag = *(const short8*)(bt + kbase);
#pragma unroll
        for (int ot = 0; ot < 2; ot++) {
            const short8 afrag = *(const short8*)(g_KSAw_bf + ((ot * 16 + n16) << 9) + kbase);
            acc[ot] = __builtin_amdgcn_mfma_f32_16x16x32_bf16(afrag, bfrag, acc[ot], 0, 0, 0);
        }
    }
#pragma unroll
    for (int ot = 0; ot < 2; ot++) {
#pragma unroll
        for (int r = 0; r < 4; r++) {
            const int o = ot * 16 + quad * 4 + r;
            g_maxout[((b * 32 + o) << 12) + p] = acc[ot][r] + Bias[o];
        }
    }
}

// q = channel max, qmean = channel mean
__global__ __launch_bounds__(256) void qstats_kernel()
{
    const int idx = blockIdx.x * 256 + threadIdx.x;  // 16384
    const int b = idx >> 12, p = idx & 4095;
    const float* mp = g_maxout + (b << 17) + p;
    float mx = -3.4e38f, s = 0.f;
#pragma unroll
    for (int j = 0; j < 32; j++) {
        const float v = mp[j << 12];
        mx = fmaxf(mx, v);
        s += v;
    }
    g_q[idx] = mx;
    g_qmean[idx] = s * (1.f / 32.f);
}

// lit[b][l] = (1/4096) * sum_i q[b][i] * flat[b][i*32+l]
__global__ __launch_bounds__(256) void lit_kernel()
{
    const int b = blockIdx.y;
    const int f0 = blockIdx.x * 8192;
    const int t = threadIdx.x;
    const float* mo = g_maxout + (b << 17);
    const float* qb = g_q + (b << 12);
    float acc = 0.f;
#pragma unroll
    for (int it = 0; it < 32; it++) {
        const int f = f0 + it * 256 + t;
        acc += qb[f >> 5] * mo[f];
    }
    __shared__ float red[256];
    red[t] = acc;
    __syncthreads();
    if (t < 32) {
        float s = 0.f;
#pragma unroll
        for (int k = 0; k < 8; k++) s += red[t + k * 32];
        atomicAdd(&g_lit[b * 32 + t], s * (1.f / 4096.f));
    }
}

// re_score -> out tail (fp32); sigfac = 1 + sigmoid(re)
__global__ __launch_bounds__(256) void rescore_kernel(float* __restrict__ out_re)
{
    const int idx = blockIdx.x * 256 + threadIdx.x;  // 16384
    const int b = idx >> 12, p = idx & 4095;
    const float* mo = g_maxout + (b << 17) + p;
    const float* lb = g_lit + b * 32;
    float r = 0.f;
#pragma unroll
    for (int j = 0; j < 32; j++) r += lb[j] * mo[j << 12];
    out_re[idx] = r;
    g_sigfac[idx] = 1.f + 1.f / (1.f + __expf(-r));
}

// ---------------------------------------------------------------------------
// Shallow conv fat GEMM from transposed bf16: Kx[b][o][s] -> .bss bf16.
// M=256 (16 o-tiles), K=256, N=16384/b. Per K-step: 1 b-load + 16 a + 16 MFMA.
// ---------------------------------------------------------------------------
__global__ __launch_bounds__(256) void gemm_kx(const float* __restrict__ Bias)
{
    const int t = threadIdx.x;
    const int wave = t >> 6, lane = t & 63;
    const int quad = lane >> 4, n16 = lane & 15;
    const int b = blockIdx.y;
    const int p = blockIdx.x * 64 + wave * 16 + n16;     // spatial 0..16383
    const u16* bt = g_shT + ((((long long)(b << 14)) + p) << 8);

    float4v acc[16];
#pragma unroll
    for (int i = 0; i < 16; i++) acc[i] = (float4v){0.f, 0.f, 0.f, 0.f};

    for (int kb = 0; kb < 8; kb++) {
        const int kbase = (kb << 5) + (quad << 3);
        const short8 bfrag = *(const short8*)(bt + kbase);
#pragma unroll
        for (int ot = 0; ot < 16; ot++) {
            const short8 afrag = *(const short8*)(g_Kw_bf + ((ot * 16 + n16) << 8) + kbase);
            acc[ot] = __builtin_amdgcn_mfma_f32_16x16x32_bf16(afrag, bfrag, acc[ot], 0, 0, 0);
        }
    }
    u16* kxb = g_Kx + (((long long)b << 8) << 14);
#pragma unroll
    for (int ot = 0; ot < 16; ot++) {
#pragma unroll
        for (int r = 0; r < 4; r++) {
            const int o = ot * 16 + quad * 4 + r;
            kxb[(o << 14) + p] = f2bf(acc[ot][r] + Bias[o]);
        }
    }
}

// ---------------------------------------------------------------------------
// Windowed softmax attention from bf16 Kx. One thread per (b,o,p_out).
// ---------------------------------------------------------------------------
__global__ __launch_bounds__(256) void att_window(float* __restrict__ out)
{
    const int p = blockIdx.x * 256 + threadIdx.x;   // 0..4095
    const int o = blockIdx.y;
    const int b = blockIdx.z;
    const int ph = p >> 6, pw = p & 63;
    const int y0 = 2 * ph - 1, x0 = 2 * pw - 1;
    const u16* kxp = g_Kx + ((((long long)b << 8) + o) << 14);

    float v[9];
#pragma unroll
    for (int ki = 0; ki < 3; ++ki) {
        const int y = y0 + ki;
        const bool yok = (y >= 0) & (y < 128);
#pragma unroll
        for (int kj = 0; kj < 3; ++kj) {
            const int x = x0 + kj;
            const bool okk = yok & (x >= 0) & (x < 128);
            v[ki * 3 + kj] = okk ? bf2f(kxp[(y << 7) + x]) : 0.f;
        }
    }
    const float m = g_qmean[(b << 12) + p];
    const float sf = g_sigfac[(b << 12) + p];
    float mx = -3.4e38f;
#pragma unroll
    for (int k = 0; k < 9; ++k) mx = fmaxf(mx, m * v[k]);
    float s = 0.f, a = 0.f;
#pragma unroll
    for (int k = 0; k < 9; ++k) {
        const float e = __expf(m * v[k] - mx);
        s += e;
        a += e * v[k];
    }
    out[((((long long)b << 8) + o) << 12) + p] = (a / s) * sf;
}

extern "C" void kernel_launch(void* const* d_in, const int* in_sizes, int n_in,
                              void* d_out, int out_size, void* d_ws, size_t ws_size,
                              hipStream_t stream) {
    const float *shallow = 0, *deep = 0, *K_w = 0, *K_b = 0, *KSA_w = 0, *KSA_b = 0;
    for (int i = 0; i < n_in; ++i) {
        switch (in_sizes[i]) {
            case 16777216: shallow = (const float*)d_in[i]; break;
            case 8388608:  deep    = (const float*)d_in[i]; break;
            case 65536:    K_w     = (const float*)d_in[i]; break;
            case 256:      K_b     = (const float*)d_in[i]; break;
            case 16384:    KSA_w   = (const float*)d_in[i]; break;
            case 32:       KSA_b   = (const float*)d_in[i]; break;
        }
    }
    float* out = (float*)d_out;   // FP32: 4194304 att + 16384 re_score

    // 0) zero lit + bf16-convert weight matrices
    prep_kernel<<<320, 256, 0, stream>>>(K_w, KSA_w);
    // 0b) transpose+cvt activations to [b][p][c] bf16 (.bss dst, device-side)
    transpose_sh<<<dim3(256, 4, 4), 256, 0, stream>>>(shallow);
    transpose_dp<<<dim3(64, 8, 4), 256, 0, stream>>>(deep);
    // 1) deep conv (MFMA, vectorized frags)
    gemm_deep<<<dim3(64, 4), 256, 0, stream>>>(KSA_b);
    // 2) per-pixel channel max/mean
    qstats_kernel<<<64, 256, 0, stream>>>();
    // 3) lit (channel-scrambled, /hw)
    lit_kernel<<<dim3(16, 4), 256, 0, stream>>>();
    // 4) re_score (fp32 -> out tail) + sigmoid factor
    rescore_kernel<<<64, 256, 0, stream>>>(out + 4194304);
    // 5) shallow conv fat GEMM -> Kx bf16 (.bss)
    gemm_kx<<<dim3(256, 4), 256, 0, stream>>>(K_b);
    // 6) windowed softmax attention + sig scaling
    att_window<<<dim3(16, 256, 4), 256, 0, stream>>>(out);
}